// Round 9
// baseline (459.638 us; speedup 1.0000x reference)
//
#include <hip/hip_runtime.h>

#define NNODES 100000
#define NEDGES 1000000
#define DIM 64
#define NGRAPHS 128
#define NLAYERS 3
#define BN_EPS 1e-5f

#define BINSZ 8
#define NBINS 12500         // 8 nodes per bin, 12500*8 == NNODES exactly
#define GBLK 256            // blocks/chunks for count/scatter passes
#define ECHUNK 3907         // ceil(NEDGES/GBLK)
#define SLICES 4            // row-slices per graph in stats

// workspace layout (4-byte element offsets, non-overlapping)
#define OFF_EDGES   0            // int2[NEDGES] = 2,000,000 ints
#define OFF_BINBASE 2000000      // int[NBINS+1]
#define OFF_YBFA    2012544      // uint[NNODES*32] = 3,200,000
#define OFF_YBFB    5212544      // uint[NNODES*32] = 3,200,000
#define OFF_XBF     8412544      // uint[NNODES*32] = 3,200,000
#define OFF_CNT     11612544     // ushort[GBLK*NBINS] = 1,600,000 ints
#define OFF_OFS     13212544     // ushort[GBLK*NBINS] = 1,600,000 ints
#define OFF_BTOT    14812544     // int[NBINS]
#define OFF_GSUM4   14825088     // float[NGRAPHS*SLICES*64] = 32768
#define OFF_PQ4     14857856     // float[32768]
#define OFF_SCALE   14890624     // float[NLAYERS*64]
#define OFF_SHIFT   14890816     // float[NLAYERS*64]
#define OFF_END     14891008     // int[NGRAPHS]
#define OFF_WQ      14891136     // float4[NLAYERS*1024] = 12288 floats
#define OFF_CTR     14903424     // int[NLAYERS]

__device__ __forceinline__ unsigned pack_bf16(float a, float b) {
    unsigned ua = __float_as_uint(a), ub = __float_as_uint(b);
    ua = (ua + 0x7FFFu + ((ua >> 16) & 1u)) >> 16;
    ub = (ub + 0x7FFFu + ((ub >> 16) & 1u)) & 0xFFFF0000u;
    return ua | ub;
}

// ---- pass 1: LDS histogram per edge-chunk -> counts[blk][bin] (ushort, contiguous);
// fused epilogues: x->bf16 pack, graph bounds, Wq build (k-chunked W copy), ctr zero ----
__global__ __launch_bounds__(1024) void count_kernel(const int* __restrict__ ei,
                                                     const float* __restrict__ x,
                                                     const int* __restrict__ batch,
                                                     const float* __restrict__ W,
                                                     unsigned short* __restrict__ counts,
                                                     unsigned* __restrict__ xbf,
                                                     int* __restrict__ endv,
                                                     float4* __restrict__ wq,
                                                     int* __restrict__ ctr) {
    __shared__ int hist[NBINS];     // 50 KB
    const int tid = threadIdx.x, blk = blockIdx.x;
    for (int i = tid; i < NBINS; i += 1024) hist[i] = 0;
    __syncthreads();
    const int e0 = blk * ECHUNK, e1 = min(NEDGES, e0 + ECHUNK);
    for (int e = e0 + tid; e < e1; e += 1024)
        atomicAdd(&hist[ei[NEDGES + e] >> 3], 1);
    __syncthreads();
    unsigned short* crow = counts + (size_t)blk * NBINS;
    for (int bin = tid; bin < NBINS; bin += 1024)
        crow[bin] = (unsigned short)hist[bin];
    const int gtid = blk * 1024 + tid;
    // fused: pack x to bf16 pairs
    for (int i = gtid; i < NNODES * 32; i += GBLK * 1024) {
        const float2 v = *(const float2*)(x + (size_t)i * 2);
        xbf[i] = pack_bf16(v.x, v.y);
    }
    // fused: per-graph end offsets from sorted batch
    for (int i = gtid; i < NNODES; i += GBLK * 1024) {
        const int b0 = batch[i];
        const int b1 = (i + 1 < NNODES) ? batch[i + 1] : NGRAPHS;
        for (int g = b0; g < b1; ++g) endv[g] = i + 1;
        if (i == 0)
            for (int g = 0; g < b0; ++g) endv[g] = 0;
    }
    // fused: Wq[l][q*64+c] = float4(W[l][c][4q..4q+3])
    for (int i = gtid; i < NLAYERS * 1024; i += GBLK * 1024) {
        const int l = i >> 10, rem = i & 1023, q = rem >> 6, c = rem & 63;
        wq[i] = *(const float4*)(W + l * 4096 + c * 64 + q * 4);
    }
    if (gtid < NLAYERS) ctr[gtid] = 0;
}

// ---- pass 2: per-bin serial scan across the 256 chunk-counts ----
__global__ __launch_bounds__(256) void s1_kernel(const unsigned short* __restrict__ counts,
                                                 unsigned short* __restrict__ offs,
                                                 int* __restrict__ btot) {
    const int bin = blockIdx.x * 256 + threadIdx.x;
    if (bin >= NBINS) return;
    int run = 0;
    for (int blk = 0; blk < GBLK; ++blk) {
        const int v = counts[(size_t)blk * NBINS + bin];
        offs[(size_t)blk * NBINS + bin] = (unsigned short)run;
        run += v;
    }
    btot[bin] = run;
}

// ---- pass 3: single-block exclusive scan over bin totals -> binBase ----
__global__ __launch_bounds__(1024) void s2_kernel(const int* __restrict__ btot,
                                                  int* __restrict__ binBase) {
    __shared__ int wsum[16];
    const int t = threadIdx.x, wid = t >> 6, lane = t & 63;
    int running = 0;
    for (int b = 0; b < NBINS; b += 1024) {
        const int i = b + t;
        const int v = (i < NBINS) ? btot[i] : 0;
        int s = v;
        for (int off = 1; off < 64; off <<= 1) {
            int x = __shfl_up(s, off);
            if (lane >= off) s += x;
        }
        __syncthreads();
        if (lane == 63) wsum[wid] = s;
        __syncthreads();
        int pw = 0, tot = 0;
#pragma unroll
        for (int k = 0; k < 16; ++k) {
            const int x = wsum[k];
            tot += x;
            if (k < wid) pw += x;
        }
        if (i < NBINS) binBase[i] = running + pw + s - v;
        running += tot;
    }
    if (t == 0) binBase[NBINS] = running;
}

// ---- pass 4: scatter edges into bin-sorted order (LDS cursors) ----
__global__ __launch_bounds__(1024) void scatter_kernel(const int* __restrict__ ei,
                                                       const float* __restrict__ ea,
                                                       const int* __restrict__ binBase,
                                                       const unsigned short* __restrict__ offs,
                                                       int2* __restrict__ edges) {
    __shared__ int cur[NBINS];      // 50 KB
    const int tid = threadIdx.x, blk = blockIdx.x;
    const unsigned short* orow = offs + (size_t)blk * NBINS;
    for (int i = tid; i < NBINS; i += 1024)
        cur[i] = binBase[i] + (int)orow[i];
    __syncthreads();
    const int e0 = blk * ECHUNK, e1 = min(NEDGES, e0 + ECHUNK);
    for (int e = e0 + tid; e < e1; e += 1024) {
        const int dst = ei[NEDGES + e];
        const int src = ei[e];
        const float w = ea[e];
        const int pos = atomicAdd(&cur[dst >> 3], 1);   // LDS atomic
        edges[pos] = make_int2((src << 3) | (dst & (BINSZ - 1)), __float_as_int(w));
    }
}

// ---- fused layer kernel: gather-aggregate (wave per 8-node bin, bf16 features,
// per-half private LDS acc) THEN in-wave 8x64 GEMM + bias + PReLU -> packed bf16 y.
// No agg round-trip through HBM; weights via L1-hot k-chunked float4 loads. ----
template <bool FIRST>
__global__ __launch_bounds__(256) void agg_gemm_kernel(const unsigned* __restrict__ hbf,
                                                       const float* __restrict__ scale,
                                                       const float* __restrict__ shift,
                                                       const int* __restrict__ binBase,
                                                       const int2* __restrict__ edges,
                                                       const float4* __restrict__ wq,
                                                       const float* __restrict__ bias,
                                                       const float* __restrict__ pa_ptr,
                                                       unsigned* __restrict__ ybf) {
    __shared__ float accAll[4][2][BINSZ * 64];   // 16 KB / block
    const int w = threadIdx.x >> 6, lane = threadIdx.x & 63;
    const int bin = blockIdx.x * 4 + w;          // grid*4 == NBINS exactly
    const int half = lane >> 5, p = lane & 31, c0 = 2 * p;
    float* ac = accAll[w][half];
#pragma unroll
    for (int r = 0; r < BINSZ; ++r) *(float2*)&ac[r * 64 + c0] = make_float2(0.f, 0.f);
    float sc0 = 1.f, sc1 = 1.f, sh0 = 0.f, sh1 = 0.f;
    if (!FIRST) { sc0 = scale[c0]; sc1 = scale[c0 + 1]; sh0 = shift[c0]; sh1 = shift[c0 + 1]; }
    const int beg = binBase[bin], end = binBase[bin + 1];
    for (int j = beg; j < end; j += 64) {
        const int n = min(64, end - j);
        int2 ed = (j + lane < end) ? edges[j + lane] : make_int2(0, 0);
        const int n16 = n & ~15;
        int t = 0;
        for (; t < n16; t += 16) {     // 16 edges per iter (8 per half), 8 loads in flight
            int sd_[8]; float wt_[8]; unsigned u_[8];
#pragma unroll
            for (int q = 0; q < 8; ++q) {
                const int ii = t + 2 * q + half;
                sd_[q] = __shfl(ed.x, ii);
                wt_[q] = __int_as_float(__shfl(ed.y, ii));
            }
#pragma unroll
            for (int q = 0; q < 8; ++q) u_[q] = hbf[(size_t)(sd_[q] >> 3) * 32 + p];
#pragma unroll
            for (int q = 0; q < 8; ++q) {
                float h0 = __uint_as_float(u_[q] << 16);
                float h1 = __uint_as_float(u_[q] & 0xFFFF0000u);
                if (!FIRST) { h0 = fmaf(h0, sc0, sh0); h1 = fmaf(h1, sc1, sh1); }
                float2* a2 = (float2*)&ac[(sd_[q] & 7) * 64 + c0];
                float2 v = *a2;
                v.x = fmaf(wt_[q], h0, v.x);
                v.y = fmaf(wt_[q], h1, v.y);
                *a2 = v;
            }
        }
        for (; t < n; t += 2) {
            const int ii = min(t + half, n - 1);
            const int sd = __shfl(ed.x, ii);
            float wt = __int_as_float(__shfl(ed.y, ii));
            if (t + half >= n) wt = 0.f;
            const unsigned u = hbf[(size_t)(sd >> 3) * 32 + p];
            float h0 = __uint_as_float(u << 16);
            float h1 = __uint_as_float(u & 0xFFFF0000u);
            if (!FIRST) { h0 = fmaf(h0, sc0, sh0); h1 = fmaf(h1, sc1, sh1); }
            float2* a2 = (float2*)&ac[(sd & 7) * 64 + c0];
            float2 v = *a2;
            v.x = fmaf(wt, h0, v.x);
            v.y = fmaf(wt, h1, v.y);
            *a2 = v;
        }
    }
    // merge halves into half0 (per-lane column, conflict-free)
    float* ac0 = accAll[w][0];
    float* ac1 = accAll[w][1];
#pragma unroll
    for (int r = 0; r < BINSZ; ++r)
        ac0[r * 64 + lane] += ac1[r * 64 + lane];
    // in-wave GEMM: lane = output column c; acc rows broadcast from LDS (wave-uniform
    // b128), weights k-chunked float4 (coalesced, L1-hot). out[r][c]=bias+sum_k A*W.
    const int c = lane;
    const float bc = bias[c];
    float o[BINSZ];
#pragma unroll
    for (int r = 0; r < BINSZ; ++r) o[r] = bc;
    for (int q = 0; q < 16; ++q) {
        const float4 wv = wq[q * 64 + c];
#pragma unroll
        for (int r = 0; r < BINSZ; ++r) {
            const float4 a4 = *(const float4*)&ac0[r * 64 + q * 4];
            o[r] = fmaf(a4.x, wv.x, o[r]);
            o[r] = fmaf(a4.y, wv.y, o[r]);
            o[r] = fmaf(a4.z, wv.z, o[r]);
            o[r] = fmaf(a4.w, wv.w, o[r]);
        }
    }
    const float pa = *pa_ptr;
#pragma unroll
    for (int r = 0; r < BINSZ; ++r) {
        const float v = (o[r] >= 0.f) ? o[r] : pa * o[r];
        ac1[r * 64 + c] = v;            // stage for pack (in-wave LDS ordering)
    }
    // pack pairs -> bf16 y; each 32-lane group writes one 128 B row segment
    const int nodeBase = bin * BINSZ;
#pragma unroll
    for (int i = 0; i < 4; ++i) {
        const int idx = lane + 64 * i;  // 0..255
        const int r = idx >> 5, p2 = idx & 31;
        ybf[(size_t)(nodeBase + r) * 32 + p2] =
            pack_bf16(ac1[r * 64 + 2 * p2], ac1[r * 64 + 2 * p2 + 1]);
    }
}

// ---- block = (graph, slice): graph-sum + channel sumsq partials; the LAST block
// (device atomic counter + threadfence) performs the BN closure + pooled output ----
__global__ __launch_bounds__(256) void statsfin_kernel(const unsigned* __restrict__ ybf,
                                                       const int* __restrict__ endv,
                                                       float* __restrict__ gsum4,
                                                       float* __restrict__ pQ4,
                                                       const float* __restrict__ bn_w,
                                                       const float* __restrict__ bn_b,
                                                       float* __restrict__ scale,
                                                       float* __restrict__ shift,
                                                       float* __restrict__ out, int layer,
                                                       int* __restrict__ ctr) {
    __shared__ float red[2][8][64];
    __shared__ int amLast;
    const int g = blockIdx.x >> 2, s = blockIdx.x & 3;
    const int tid = threadIdx.x, rl = tid >> 5, p = tid & 31, c0 = 2 * p;
    const int g0 = (g == 0) ? 0 : endv[g - 1];
    const int g1 = endv[g];
    const int len = g1 - g0;
    const int q0 = g0 + (len * s) / SLICES;
    const int q1 = g0 + (len * (s + 1)) / SLICES;
    float ga0 = 0.f, ga1 = 0.f, qq0 = 0.f, qq1 = 0.f;
    for (int r = q0 + rl; r < q1; r += 8) {
        const unsigned u = ybf[(size_t)r * 32 + p];
        const float f0 = __uint_as_float(u << 16);
        const float f1 = __uint_as_float(u & 0xFFFF0000u);
        ga0 += f0; ga1 += f1;
        qq0 = fmaf(f0, f0, qq0); qq1 = fmaf(f1, f1, qq1);
    }
    red[0][rl][c0] = ga0; red[0][rl][c0 + 1] = ga1;
    red[1][rl][c0] = qq0; red[1][rl][c0 + 1] = qq1;
    __syncthreads();
    if (rl == 0) {
        float a0 = 0.f, a1 = 0.f, b0 = 0.f, b1 = 0.f;
#pragma unroll
        for (int k = 0; k < 8; ++k) {
            a0 += red[0][k][c0]; a1 += red[0][k][c0 + 1];
            b0 += red[1][k][c0]; b1 += red[1][k][c0 + 1];
        }
        gsum4[blockIdx.x * 64 + c0] = a0; gsum4[blockIdx.x * 64 + c0 + 1] = a1;
        pQ4[blockIdx.x * 64 + c0] = b0;  pQ4[blockIdx.x * 64 + c0 + 1] = b1;
    }
    // last-block finalize
    __threadfence();
    if (tid == 0) amLast = (atomicAdd(ctr, 1) == NGRAPHS * SLICES - 1);
    __syncthreads();
    if (!amLast) return;
    __threadfence();
    __shared__ float rS[4][64], rQ[4][64];
    __shared__ float ssc[64], ssh[64];
    const int c = tid & 63, pp = tid >> 6;    // pp in 0..3
    float S = 0.f, Q = 0.f;
    for (int sl = pp; sl < NGRAPHS * SLICES; sl += 4) {
        S += gsum4[sl * 64 + c];
        Q += pQ4[sl * 64 + c];
    }
    rS[pp][c] = S; rQ[pp][c] = Q;
    __syncthreads();
    if (tid < 64) {
        float SS = 0.f, QQ = 0.f;
#pragma unroll
        for (int k = 0; k < 4; ++k) { SS += rS[k][c]; QQ += rQ[k][c]; }
        const float mean = SS * (1.f / NNODES);
        const float var = fmaxf(QQ * (1.f / NNODES) - mean * mean, 0.f);
        const float inv = rsqrtf(var + BN_EPS);
        const float scv = inv * bn_w[c];
        const float shv = bn_b[c] - mean * scv;
        ssc[c] = scv; ssh[c] = shv;
        scale[c] = scv; shift[c] = shv;
    }
    __syncthreads();
    for (int idx = tid; idx < NGRAPHS * 64; idx += 256) {
        const int gg = idx >> 6, ch = idx & 63;
        float gs = 0.f;
#pragma unroll
        for (int sl = 0; sl < SLICES; ++sl) gs += gsum4[(gg * SLICES + sl) * 64 + ch];
        const int cnt = endv[gg] - ((gg == 0) ? 0 : endv[gg - 1]);
        const float pooled = gs * ssc[ch] + (float)cnt * ssh[ch];
        out[gg * (NLAYERS * 64) + layer * 64 + ch] = pooled;
        if (layer == NLAYERS - 1) out[NGRAPHS * NLAYERS * 64 + idx] = pooled;
    }
}

extern "C" void kernel_launch(void* const* d_in, const int* in_sizes, int n_in,
                              void* d_out, int out_size, void* d_ws, size_t ws_size,
                              hipStream_t stream) {
    const float* x     = (const float*)d_in[0];
    const int*   ei    = (const int*)d_in[1];
    const float* ea    = (const float*)d_in[2];
    const int*   batch = (const int*)d_in[3];
    const float* W     = (const float*)d_in[4];
    const float* b     = (const float*)d_in[5];
    const float* pa    = (const float*)d_in[6];
    const float* bn_w  = (const float*)d_in[7];
    const float* bn_b  = (const float*)d_in[8];
    float* out = (float*)d_out;
    float* ws  = (float*)d_ws;
    int*   wsi = (int*)d_ws;

    int2*           edges   = (int2*)(wsi + OFF_EDGES);
    int*            binBase = wsi + OFF_BINBASE;
    unsigned*       ybfA    = (unsigned*)(wsi + OFF_YBFA);
    unsigned*       ybfB    = (unsigned*)(wsi + OFF_YBFB);
    unsigned*       xbf     = (unsigned*)(wsi + OFF_XBF);
    unsigned short* counts  = (unsigned short*)(wsi + OFF_CNT);
    unsigned short* offs    = (unsigned short*)(wsi + OFF_OFS);
    int*            btot    = wsi + OFF_BTOT;
    float*          gsum4   = ws + OFF_GSUM4;
    float*          pQ4     = ws + OFF_PQ4;
    float*          scaleA  = ws + OFF_SCALE;
    float*          shiftA  = ws + OFF_SHIFT;
    int*            endv    = wsi + OFF_END;
    float4*         wq      = (float4*)(ws + OFF_WQ);
    int*            ctr     = wsi + OFF_CTR;

    count_kernel<<<GBLK, 1024, 0, stream>>>(ei, x, batch, W, counts, xbf, endv, wq, ctr);
    s1_kernel<<<(NBINS + 255) / 256, 256, 0, stream>>>(counts, offs, btot);
    s2_kernel<<<1, 1024, 0, stream>>>(btot, binBase);
    scatter_kernel<<<GBLK, 1024, 0, stream>>>(ei, ea, binBase, offs, edges);

    const unsigned* inb = xbf;
    for (int l = 0; l < NLAYERS; ++l) {
        unsigned* outb = (l & 1) ? ybfB : ybfA;
        if (l == 0)
            agg_gemm_kernel<true><<<NBINS / 4, 256, 0, stream>>>(
                inb, nullptr, nullptr, binBase, edges, wq, b, pa, outb);
        else
            agg_gemm_kernel<false><<<NBINS / 4, 256, 0, stream>>>(
                inb, scaleA + (l - 1) * 64, shiftA + (l - 1) * 64, binBase, edges,
                wq + (size_t)l * 1024, b + l * 64, pa, outb);
        statsfin_kernel<<<NGRAPHS * SLICES, 256, 0, stream>>>(
            outb, endv, gsum4, pQ4, bn_w + l * 64, bn_b + l * 64,
            scaleA + l * 64, shiftA + l * 64, out, l, ctr + l);
        inb = outb;
    }
}

// Round 12
// 309.060 us; speedup vs baseline: 1.4872x; 1.4872x over previous
//
#include <hip/hip_runtime.h>

#define NNODES 100000
#define NEDGES 1000000
#define DIM 64
#define NGRAPHS 128
#define NLAYERS 3
#define BN_EPS 1e-5f

#define BINSZ 8
#define NBINS 12500         // 8 nodes per bin, 12500*8 == NNODES exactly
#define GBLK 256            // blocks/chunks for count/scatter passes
#define ECHUNK 3907         // ceil(NEDGES/GBLK)
#define SLICES 4            // row-slices per graph in stats

// workspace layout (4-byte element offsets, non-overlapping; ws >= 268 MB)
#define OFF_EDGES   0            // int2[NEDGES] = 2,000,000 ints
#define OFF_BINBASE 2000000      // int[NBINS+1]
#define OFF_AGG     2012544      // float[NNODES*64] = 6,400,000
#define OFF_YBF     8412544      // uint[NNODES*32] = 3,200,000 (bf16-packed y)
#define OFF_XBF     11612544     // uint[NNODES*32] = 3,200,000 (bf16-packed x)
#define OFF_CNT     14812544     // ushort[GBLK*NBINS] = 1,600,000 ints
#define OFF_OFS     16412544     // ushort[GBLK*NBINS] = 1,600,000 ints
#define OFF_BTOT    18012544     // int[NBINS]
#define OFF_GSUM4   18025088     // float[NGRAPHS*SLICES*64] = 32768
#define OFF_PQ4     18057856     // float[32768]
#define OFF_SCALE   18090624     // float[NLAYERS*64]
#define OFF_SHIFT   18090816     // float[NLAYERS*64]
#define OFF_END     18091008     // int[NGRAPHS]

__device__ __forceinline__ unsigned pack_bf16(float a, float b) {
    unsigned ua = __float_as_uint(a), ub = __float_as_uint(b);
    ua = (ua + 0x7FFFu + ((ua >> 16) & 1u)) >> 16;
    ub = (ub + 0x7FFFu + ((ub >> 16) & 1u)) & 0xFFFF0000u;
    return ua | ub;
}

// ---- pass 1: LDS histogram per edge-chunk -> counts[blk][bin] (ushort, contiguous);
// fused grid-stride epilogues: x -> packed bf16, per-graph bounds ----
__global__ __launch_bounds__(1024) void count_kernel(const int* __restrict__ ei,
                                                     const float* __restrict__ x,
                                                     const int* __restrict__ batch,
                                                     unsigned short* __restrict__ counts,
                                                     unsigned* __restrict__ xbf,
                                                     int* __restrict__ endv) {
    __shared__ int hist[NBINS];     // 50 KB
    const int tid = threadIdx.x, blk = blockIdx.x;
    for (int i = tid; i < NBINS; i += 1024) hist[i] = 0;
    __syncthreads();
    const int e0 = blk * ECHUNK, e1 = min(NEDGES, e0 + ECHUNK);
    for (int e = e0 + tid; e < e1; e += 1024)
        atomicAdd(&hist[ei[NEDGES + e] >> 3], 1);
    __syncthreads();
    unsigned short* crow = counts + (size_t)blk * NBINS;
    for (int bin = tid; bin < NBINS; bin += 1024)
        crow[bin] = (unsigned short)hist[bin];
    // fused: pack x to bf16 pairs
    const int gtid = blk * 1024 + tid;
    for (int i = gtid; i < NNODES * 32; i += GBLK * 1024) {
        const float2 v = *(const float2*)(x + (size_t)i * 2);
        xbf[i] = pack_bf16(v.x, v.y);
    }
    // fused: per-graph end offsets from sorted batch
    for (int i = gtid; i < NNODES; i += GBLK * 1024) {
        const int b0 = batch[i];
        const int b1 = (i + 1 < NNODES) ? batch[i + 1] : NGRAPHS;
        for (int g = b0; g < b1; ++g) endv[g] = i + 1;
        if (i == 0)
            for (int g = 0; g < b0; ++g) endv[g] = 0;
    }
}

// ---- pass 2: per-bin serial scan across the 256 chunk-counts (thread per bin,
// coalesced across lanes) -> offs[blk][bin] + bin totals ----
__global__ __launch_bounds__(256) void s1_kernel(const unsigned short* __restrict__ counts,
                                                 unsigned short* __restrict__ offs,
                                                 int* __restrict__ btot) {
    const int bin = blockIdx.x * 256 + threadIdx.x;
    if (bin >= NBINS) return;
    int run = 0;
    for (int blk = 0; blk < GBLK; ++blk) {
        const int v = counts[(size_t)blk * NBINS + bin];
        offs[(size_t)blk * NBINS + bin] = (unsigned short)run;
        run += v;
    }
    btot[bin] = run;
}

// ---- pass 3: single-block exclusive scan over bin totals -> binBase ----
__global__ __launch_bounds__(1024) void s2_kernel(const int* __restrict__ btot,
                                                  int* __restrict__ binBase) {
    __shared__ int wsum[16];
    const int t = threadIdx.x, wid = t >> 6, lane = t & 63;
    int running = 0;
    for (int b = 0; b < NBINS; b += 1024) {
        const int i = b + t;
        const int v = (i < NBINS) ? btot[i] : 0;
        int s = v;
        for (int off = 1; off < 64; off <<= 1) {
            int x = __shfl_up(s, off);
            if (lane >= off) s += x;
        }
        __syncthreads();
        if (lane == 63) wsum[wid] = s;
        __syncthreads();
        int pw = 0, tot = 0;
#pragma unroll
        for (int k = 0; k < 16; ++k) {
            const int x = wsum[k];
            tot += x;
            if (k < wid) pw += x;
        }
        if (i < NBINS) binBase[i] = running + pw + s - v;
        running += tot;
    }
    if (t == 0) binBase[NBINS] = running;
}

// ---- pass 4: scatter edges into bin-sorted order (LDS cursors, no global atomics) ----
__global__ __launch_bounds__(1024) void scatter_kernel(const int* __restrict__ ei,
                                                       const float* __restrict__ ea,
                                                       const int* __restrict__ binBase,
                                                       const unsigned short* __restrict__ offs,
                                                       int2* __restrict__ edges) {
    __shared__ int cur[NBINS];      // 50 KB
    const int tid = threadIdx.x, blk = blockIdx.x;
    const unsigned short* orow = offs + (size_t)blk * NBINS;
    for (int i = tid; i < NBINS; i += 1024)
        cur[i] = binBase[i] + (int)orow[i];
    __syncthreads();
    const int e0 = blk * ECHUNK, e1 = min(NEDGES, e0 + ECHUNK);
    for (int e = e0 + tid; e < e1; e += 1024) {
        const int dst = ei[NEDGES + e];
        const int src = ei[e];
        const float w = ea[e];
        const int pos = atomicAdd(&cur[dst >> 3], 1);   // LDS atomic
        edges[pos] = make_int2((src << 3) | (dst & (BINSZ - 1)), __float_as_int(w));
    }
}

// ---- aggregation: wave per 8-node bin; half-wave per bf16-packed row (2 edges per
// wave-load); 16-edge unroll = 8 gathers in flight per half; per-half private LDS
// accumulators merged at the end (no atomics, no races) ----
template <bool FIRST>
__global__ __launch_bounds__(256) void agg_kernel(const unsigned* __restrict__ hbf,
                                                  const float* __restrict__ scale,
                                                  const float* __restrict__ shift,
                                                  const int* __restrict__ binBase,
                                                  const int2* __restrict__ edges,
                                                  float* __restrict__ agg) {
    __shared__ float accAll[4][2][BINSZ * 64];   // 16 KB / block
    const int w = threadIdx.x >> 6, lane = threadIdx.x & 63;
    const int bin = blockIdx.x * 4 + w;          // grid*4 == NBINS exactly
    const int half = lane >> 5, p = lane & 31, c0 = 2 * p;
    float* ac = accAll[w][half];
#pragma unroll
    for (int r = 0; r < BINSZ; ++r) *(float2*)&ac[r * 64 + c0] = make_float2(0.f, 0.f);
    float sc0 = 1.f, sc1 = 1.f, sh0 = 0.f, sh1 = 0.f;
    if (!FIRST) { sc0 = scale[c0]; sc1 = scale[c0 + 1]; sh0 = shift[c0]; sh1 = shift[c0 + 1]; }
    const int beg = binBase[bin], end = binBase[bin + 1];
    for (int j = beg; j < end; j += 64) {
        const int n = min(64, end - j);
        int2 ed = (j + lane < end) ? edges[j + lane] : make_int2(0, 0);
        const int n16 = n & ~15;
        int t = 0;
        for (; t < n16; t += 16) {     // 16 edges per iter (8 per half), 8 loads in flight
            int sd_[8]; float wt_[8]; unsigned u_[8];
#pragma unroll
            for (int q = 0; q < 8; ++q) {
                const int ii = t + 2 * q + half;
                sd_[q] = __shfl(ed.x, ii);
                wt_[q] = __int_as_float(__shfl(ed.y, ii));
            }
#pragma unroll
            for (int q = 0; q < 8; ++q) u_[q] = hbf[(size_t)(sd_[q] >> 3) * 32 + p];
#pragma unroll
            for (int q = 0; q < 8; ++q) {
                float h0 = __uint_as_float(u_[q] << 16);
                float h1 = __uint_as_float(u_[q] & 0xFFFF0000u);
                if (!FIRST) { h0 = fmaf(h0, sc0, sh0); h1 = fmaf(h1, sc1, sh1); }
                float2* a2 = (float2*)&ac[(sd_[q] & 7) * 64 + c0];
                float2 v = *a2;
                v.x = fmaf(wt_[q], h0, v.x);
                v.y = fmaf(wt_[q], h1, v.y);
                *a2 = v;
            }
        }
        for (; t < n; t += 2) {
            const int ii = min(t + half, n - 1);
            const int sd = __shfl(ed.x, ii);
            float wt = __int_as_float(__shfl(ed.y, ii));
            if (t + half >= n) wt = 0.f;
            const unsigned u = hbf[(size_t)(sd >> 3) * 32 + p];
            float h0 = __uint_as_float(u << 16);
            float h1 = __uint_as_float(u & 0xFFFF0000u);
            if (!FIRST) { h0 = fmaf(h0, sc0, sh0); h1 = fmaf(h1, sc1, sh1); }
            float2* a2 = (float2*)&ac[(sd & 7) * 64 + c0];
            float2 v = *a2;
            v.x = fmaf(wt, h0, v.x);
            v.y = fmaf(wt, h1, v.y);
            *a2 = v;
        }
    }
    const int nodeBase = bin * BINSZ;
#pragma unroll
    for (int r = 0; r < BINSZ; ++r)
        agg[(size_t)(nodeBase + r) * 64 + lane] =
            accAll[w][0][r * 64 + lane] + accAll[w][1][r * 64 + lane];
}

// ---- y = PReLU(agg @ W^T + bias) -> packed bf16. LDS-tiled SGEMM:
// block = 128 rows x 64 cols, thread = 4 rows (stride 32) x 8 cols. ----
__global__ __launch_bounds__(256) void gemm_kernel(const float* __restrict__ agg,
                                                   const float* __restrict__ W,
                                                   const float* __restrict__ bias,
                                                   const float* __restrict__ pa_ptr,
                                                   unsigned* __restrict__ ybf) {
    __shared__ float As[128 * 68];
    __shared__ float Wt[64 * 68];
    const int tid = threadIdx.x;
    const int base = blockIdx.x * 128;
    for (int i = tid; i < 2048; i += 256) {
        const int r = i >> 4;
        const int q = (i & 15) * 4;
        const int row = base + r;
        float4 v = make_float4(0.f, 0.f, 0.f, 0.f);
        if (row < NNODES) v = *(const float4*)(agg + (size_t)row * 64 + q);
        *(float4*)&As[r * 68 + q] = v;
    }
    for (int i = tid; i < 4096; i += 256)
        Wt[(i & 63) * 68 + (i >> 6)] = W[i];
    __syncthreads();

    const int tc = tid & 7;
    const int tr = tid >> 3;
    float acc[4][8];
#pragma unroll
    for (int j = 0; j < 4; ++j)
#pragma unroll
        for (int c = 0; c < 8; ++c) acc[j][c] = 0.f;

    for (int kc = 0; kc < 16; ++kc) {
        const int k0 = kc * 4;
        float Af[4][4];
#pragma unroll
        for (int j = 0; j < 4; ++j) {
            const float4 t = *(const float4*)&As[(tr + 32 * j) * 68 + k0];
            Af[j][0] = t.x; Af[j][1] = t.y; Af[j][2] = t.z; Af[j][3] = t.w;
        }
#pragma unroll
        for (int kk = 0; kk < 4; ++kk) {
            const float4 w0 = *(const float4*)&Wt[(k0 + kk) * 68 + tc * 8];
            const float4 w1 = *(const float4*)&Wt[(k0 + kk) * 68 + tc * 8 + 4];
#pragma unroll
            for (int j = 0; j < 4; ++j) {
                const float a = Af[j][kk];
                acc[j][0] = fmaf(a, w0.x, acc[j][0]);
                acc[j][1] = fmaf(a, w0.y, acc[j][1]);
                acc[j][2] = fmaf(a, w0.z, acc[j][2]);
                acc[j][3] = fmaf(a, w0.w, acc[j][3]);
                acc[j][4] = fmaf(a, w1.x, acc[j][4]);
                acc[j][5] = fmaf(a, w1.y, acc[j][5]);
                acc[j][6] = fmaf(a, w1.z, acc[j][6]);
                acc[j][7] = fmaf(a, w1.w, acc[j][7]);
            }
        }
    }

    const float pa = *pa_ptr;
    const float4 b0 = *(const float4*)(bias + tc * 8);
    const float4 b1 = *(const float4*)(bias + tc * 8 + 4);
#pragma unroll
    for (int j = 0; j < 4; ++j) {
        const int row = base + tr + 32 * j;
        if (row >= NNODES) continue;
        float o[8];
        o[0] = acc[j][0] + b0.x; o[1] = acc[j][1] + b0.y;
        o[2] = acc[j][2] + b0.z; o[3] = acc[j][3] + b0.w;
        o[4] = acc[j][4] + b1.x; o[5] = acc[j][5] + b1.y;
        o[6] = acc[j][6] + b1.z; o[7] = acc[j][7] + b1.w;
#pragma unroll
        for (int c = 0; c < 8; ++c) o[c] = (o[c] >= 0.f) ? o[c] : pa * o[c];
        uint4 pk;
        pk.x = pack_bf16(o[0], o[1]);
        pk.y = pack_bf16(o[2], o[3]);
        pk.z = pack_bf16(o[4], o[5]);
        pk.w = pack_bf16(o[6], o[7]);
        *(uint4*)(ybf + (size_t)row * 32 + tc * 4) = pk;
    }
}

// ---- block = (graph, slice): graph-sum + channel sumsq from packed y.
// graph-sum partials double as BN channel-sum partials (same rows). ----
__global__ __launch_bounds__(256) void stats_kernel(const unsigned* __restrict__ ybf,
                                                    const int* __restrict__ endv,
                                                    float* __restrict__ gsum4,
                                                    float* __restrict__ pQ4) {
    __shared__ float red[2][8][64];
    const int g = blockIdx.x >> 2, s = blockIdx.x & 3;
    const int t = threadIdx.x, rl = t >> 5, p = t & 31, c0 = 2 * p;
    const int g0 = (g == 0) ? 0 : endv[g - 1];
    const int g1 = endv[g];
    const int len = g1 - g0;
    const int q0 = g0 + (len * s) / SLICES;
    const int q1 = g0 + (len * (s + 1)) / SLICES;
    float ga0 = 0.f, ga1 = 0.f, qq0 = 0.f, qq1 = 0.f;
    for (int r = q0 + rl; r < q1; r += 8) {
        const unsigned u = ybf[(size_t)r * 32 + p];
        const float f0 = __uint_as_float(u << 16);
        const float f1 = __uint_as_float(u & 0xFFFF0000u);
        ga0 += f0; ga1 += f1;
        qq0 = fmaf(f0, f0, qq0); qq1 = fmaf(f1, f1, qq1);
    }
    red[0][rl][c0] = ga0; red[0][rl][c0 + 1] = ga1;
    red[1][rl][c0] = qq0; red[1][rl][c0 + 1] = qq1;
    __syncthreads();
    if (rl == 0) {
        float a0 = 0.f, a1 = 0.f, b0 = 0.f, b1 = 0.f;
#pragma unroll
        for (int k = 0; k < 8; ++k) {
            a0 += red[0][k][c0]; a1 += red[0][k][c0 + 1];
            b0 += red[1][k][c0]; b1 += red[1][k][c0 + 1];
        }
        gsum4[blockIdx.x * 64 + c0] = a0; gsum4[blockIdx.x * 64 + c0 + 1] = a1;
        pQ4[blockIdx.x * 64 + c0] = b0;  pQ4[blockIdx.x * 64 + c0 + 1] = b1;
    }
}

// ---- single block: BN closure + pooled outputs straight into d_out ----
__global__ __launch_bounds__(512) void finalize_kernel(const float* __restrict__ gsum4,
                                                       const float* __restrict__ pQ4,
                                                       const int* __restrict__ endv,
                                                       const float* __restrict__ bn_w,
                                                       const float* __restrict__ bn_b,
                                                       float* __restrict__ scale,
                                                       float* __restrict__ shift,
                                                       float* __restrict__ out, int layer) {
    __shared__ float rS[8][64], rQ[8][64];
    __shared__ float ssc[64], ssh[64];
    const int tid = threadIdx.x;
    const int c = tid & 63, pp = tid >> 6;    // pp in 0..7
    float S = 0.f, Q = 0.f;
    for (int sl = pp; sl < NGRAPHS * SLICES; sl += 8) {
        S += gsum4[sl * 64 + c];
        Q += pQ4[sl * 64 + c];
    }
    rS[pp][c] = S; rQ[pp][c] = Q;
    __syncthreads();
    if (tid < 64) {
        float SS = 0.f, QQ = 0.f;
#pragma unroll
        for (int k = 0; k < 8; ++k) { SS += rS[k][c]; QQ += rQ[k][c]; }
        const float mean = SS * (1.f / NNODES);
        const float var = fmaxf(QQ * (1.f / NNODES) - mean * mean, 0.f);
        const float inv = rsqrtf(var + BN_EPS);
        const float scv = inv * bn_w[c];
        const float shv = bn_b[c] - mean * scv;
        ssc[c] = scv; ssh[c] = shv;
        scale[c] = scv; shift[c] = shv;
    }
    __syncthreads();
    for (int idx = tid; idx < NGRAPHS * 64; idx += 512) {
        const int g = idx >> 6, ch = idx & 63;
        float gs = 0.f;
#pragma unroll
        for (int sl = 0; sl < SLICES; ++sl) gs += gsum4[(g * SLICES + sl) * 64 + ch];
        const int cnt = endv[g] - ((g == 0) ? 0 : endv[g - 1]);
        const float pooled = gs * ssc[ch] + (float)cnt * ssh[ch];
        out[g * (NLAYERS * 64) + layer * 64 + ch] = pooled;
        if (layer == NLAYERS - 1) out[NGRAPHS * NLAYERS * 64 + idx] = pooled;
    }
}

extern "C" void kernel_launch(void* const* d_in, const int* in_sizes, int n_in,
                              void* d_out, int out_size, void* d_ws, size_t ws_size,
                              hipStream_t stream) {
    const float* x     = (const float*)d_in[0];
    const int*   ei    = (const int*)d_in[1];
    const float* ea    = (const float*)d_in[2];
    const int*   batch = (const int*)d_in[3];
    const float* W     = (const float*)d_in[4];
    const float* b     = (const float*)d_in[5];
    const float* pa    = (const float*)d_in[6];
    const float* bn_w  = (const float*)d_in[7];
    const float* bn_b  = (const float*)d_in[8];
    float* out = (float*)d_out;
    float* ws  = (float*)d_ws;
    int*   wsi = (int*)d_ws;

    int2*           edges   = (int2*)(wsi + OFF_EDGES);
    int*            binBase = wsi + OFF_BINBASE;
    float*          agg     = ws + OFF_AGG;
    unsigned*       ybf     = (unsigned*)(wsi + OFF_YBF);
    unsigned*       xbf     = (unsigned*)(wsi + OFF_XBF);
    unsigned short* counts  = (unsigned short*)(wsi + OFF_CNT);
    unsigned short* offs    = (unsigned short*)(wsi + OFF_OFS);
    int*            btot    = wsi + OFF_BTOT;
    float*          gsum4   = ws + OFF_GSUM4;
    float*          pQ4     = ws + OFF_PQ4;
    float*          scaleA  = ws + OFF_SCALE;
    float*          shiftA  = ws + OFF_SHIFT;
    int*            endv    = wsi + OFF_END;

    count_kernel<<<GBLK, 1024, 0, stream>>>(ei, x, batch, counts, xbf, endv);
    s1_kernel<<<(NBINS + 255) / 256, 256, 0, stream>>>(counts, offs, btot);
    s2_kernel<<<1, 1024, 0, stream>>>(btot, binBase);
    scatter_kernel<<<GBLK, 1024, 0, stream>>>(ei, ea, binBase, offs, edges);

    for (int l = 0; l < NLAYERS; ++l) {
        if (l == 0)
            agg_kernel<true><<<NBINS / 4, 256, 0, stream>>>(xbf, nullptr, nullptr,
                                                            binBase, edges, agg);
        else
            agg_kernel<false><<<NBINS / 4, 256, 0, stream>>>(ybf, scaleA + (l - 1) * 64,
                                                             shiftA + (l - 1) * 64,
                                                             binBase, edges, agg);
        gemm_kernel<<<(NNODES + 127) / 128, 256, 0, stream>>>(agg, W + l * 4096, b + l * 64,
                                                              pa, ybf);
        stats_kernel<<<NGRAPHS * SLICES, 256, 0, stream>>>(ybf, endv, gsum4, pQ4);
        finalize_kernel<<<1, 512, 0, stream>>>(gsum4, pQ4, endv, bn_w + l * 64,
                                               bn_b + l * 64, scaleA + l * 64,
                                               shiftA + l * 64, out, l);
    }
}

// Round 13
// 294.552 us; speedup vs baseline: 1.5605x; 1.0493x over previous
//
#include <hip/hip_runtime.h>

#define NNODES 100000
#define NEDGES 1000000
#define DIM 64
#define NGRAPHS 128
#define NLAYERS 3
#define BN_EPS 1e-5f

#define BINSZ 8
#define NBINS 12500         // 8 nodes per bin, 12500*8 == NNODES exactly
#define GBLK 256            // blocks/chunks for count/scatter passes
#define ECHUNK 3907         // ceil(NEDGES/GBLK)
#define SLICES 4            // row-slices per graph in stats

// workspace layout (4-byte element offsets, non-overlapping; ws >= 268 MB)
#define OFF_EDGES   0            // int2[NEDGES] = 2,000,000 ints
#define OFF_BINBASE 2000000      // int[NBINS+1]
#define OFF_AGG     2012544      // float[NNODES*64] = 6,400,000
#define OFF_YBF     8412544      // uint[NNODES*32] = 3,200,000 (bf16-packed y)
#define OFF_XBF     11612544     // uint[NNODES*32] = 3,200,000 (bf16-packed x)
#define OFF_CNT     14812544     // ushort[GBLK*NBINS] = 1,600,000 ints
#define OFF_OFS     16412544     // ushort[GBLK*NBINS] = 1,600,000 ints
#define OFF_BTOT    18012544     // int[NBINS]
#define OFF_GSUM4   18025088     // float[NGRAPHS*SLICES*64] = 32768
#define OFF_PQ4     18057856     // float[32768]
#define OFF_SCALE   18090624     // float[NLAYERS*64]
#define OFF_SHIFT   18090816     // float[NLAYERS*64]
#define OFF_END     18091008     // int[NGRAPHS]

__device__ __forceinline__ unsigned pack_bf16(float a, float b) {
    unsigned ua = __float_as_uint(a), ub = __float_as_uint(b);
    ua = (ua + 0x7FFFu + ((ua >> 16) & 1u)) >> 16;
    ub = (ub + 0x7FFFu + ((ub >> 16) & 1u)) & 0xFFFF0000u;
    return ua | ub;
}

// ---- pass 1: LDS histogram per edge-chunk -> counts[blk][bin] (ushort, contiguous);
// fused grid-stride epilogues: x -> packed bf16, per-graph bounds ----
__global__ __launch_bounds__(1024) void count_kernel(const int* __restrict__ ei,
                                                     const float* __restrict__ x,
                                                     const int* __restrict__ batch,
                                                     unsigned short* __restrict__ counts,
                                                     unsigned* __restrict__ xbf,
                                                     int* __restrict__ endv) {
    __shared__ int hist[NBINS];     // 50 KB
    const int tid = threadIdx.x, blk = blockIdx.x;
    for (int i = tid; i < NBINS; i += 1024) hist[i] = 0;
    __syncthreads();
    const int e0 = blk * ECHUNK, e1 = min(NEDGES, e0 + ECHUNK);
    for (int e = e0 + tid; e < e1; e += 1024)
        atomicAdd(&hist[ei[NEDGES + e] >> 3], 1);
    __syncthreads();
    unsigned short* crow = counts + (size_t)blk * NBINS;
    for (int bin = tid; bin < NBINS; bin += 1024)
        crow[bin] = (unsigned short)hist[bin];
    // fused: pack x to bf16 pairs
    const int gtid = blk * 1024 + tid;
    for (int i = gtid; i < NNODES * 32; i += GBLK * 1024) {
        const float2 v = *(const float2*)(x + (size_t)i * 2);
        xbf[i] = pack_bf16(v.x, v.y);
    }
    // fused: per-graph end offsets from sorted batch
    for (int i = gtid; i < NNODES; i += GBLK * 1024) {
        const int b0 = batch[i];
        const int b1 = (i + 1 < NNODES) ? batch[i + 1] : NGRAPHS;
        for (int g = b0; g < b1; ++g) endv[g] = i + 1;
        if (i == 0)
            for (int g = 0; g < b0; ++g) endv[g] = 0;
    }
}

// ---- pass 2: per-bin serial scan across the 256 chunk-counts (thread per bin,
// coalesced across lanes) -> offs[blk][bin] + bin totals ----
__global__ __launch_bounds__(256) void s1_kernel(const unsigned short* __restrict__ counts,
                                                 unsigned short* __restrict__ offs,
                                                 int* __restrict__ btot) {
    const int bin = blockIdx.x * 256 + threadIdx.x;
    if (bin >= NBINS) return;
    int run = 0;
    for (int blk = 0; blk < GBLK; ++blk) {
        const int v = counts[(size_t)blk * NBINS + bin];
        offs[(size_t)blk * NBINS + bin] = (unsigned short)run;
        run += v;
    }
    btot[bin] = run;
}

// ---- pass 3: single-block exclusive scan over bin totals -> binBase ----
__global__ __launch_bounds__(1024) void s2_kernel(const int* __restrict__ btot,
                                                  int* __restrict__ binBase) {
    __shared__ int wsum[16];
    const int t = threadIdx.x, wid = t >> 6, lane = t & 63;
    int running = 0;
    for (int b = 0; b < NBINS; b += 1024) {
        const int i = b + t;
        const int v = (i < NBINS) ? btot[i] : 0;
        int s = v;
        for (int off = 1; off < 64; off <<= 1) {
            int x = __shfl_up(s, off);
            if (lane >= off) s += x;
        }
        __syncthreads();
        if (lane == 63) wsum[wid] = s;
        __syncthreads();
        int pw = 0, tot = 0;
#pragma unroll
        for (int k = 0; k < 16; ++k) {
            const int x = wsum[k];
            tot += x;
            if (k < wid) pw += x;
        }
        if (i < NBINS) binBase[i] = running + pw + s - v;
        running += tot;
    }
    if (t == 0) binBase[NBINS] = running;
}

// ---- pass 4: scatter edges into bin-sorted order (LDS cursors, no global atomics) ----
__global__ __launch_bounds__(1024) void scatter_kernel(const int* __restrict__ ei,
                                                       const float* __restrict__ ea,
                                                       const int* __restrict__ binBase,
                                                       const unsigned short* __restrict__ offs,
                                                       int2* __restrict__ edges) {
    __shared__ int cur[NBINS];      // 50 KB
    const int tid = threadIdx.x, blk = blockIdx.x;
    const unsigned short* orow = offs + (size_t)blk * NBINS;
    for (int i = tid; i < NBINS; i += 1024)
        cur[i] = binBase[i] + (int)orow[i];
    __syncthreads();
    const int e0 = blk * ECHUNK, e1 = min(NEDGES, e0 + ECHUNK);
    for (int e = e0 + tid; e < e1; e += 1024) {
        const int dst = ei[NEDGES + e];
        const int src = ei[e];
        const float w = ea[e];
        const int pos = atomicAdd(&cur[dst >> 3], 1);   // LDS atomic
        edges[pos] = make_int2((src << 3) | (dst & (BINSZ - 1)), __float_as_int(w));
    }
}

// ---- aggregation: wave per 8-node bin; half-wave per bf16-packed row (2 edges per
// wave-load); 16-edge unroll = 8 gathers in flight per half; per-half private LDS
// accumulators merged at the end (no atomics, no races) ----
template <bool FIRST>
__global__ __launch_bounds__(256) void agg_kernel(const unsigned* __restrict__ hbf,
                                                  const float* __restrict__ scale,
                                                  const float* __restrict__ shift,
                                                  const int* __restrict__ binBase,
                                                  const int2* __restrict__ edges,
                                                  float* __restrict__ agg) {
    __shared__ float accAll[4][2][BINSZ * 64];   // 16 KB / block
    const int w = threadIdx.x >> 6, lane = threadIdx.x & 63;
    const int bin = blockIdx.x * 4 + w;          // grid*4 == NBINS exactly
    const int half = lane >> 5, p = lane & 31, c0 = 2 * p;
    float* ac = accAll[w][half];
#pragma unroll
    for (int r = 0; r < BINSZ; ++r) *(float2*)&ac[r * 64 + c0] = make_float2(0.f, 0.f);
    float sc0 = 1.f, sc1 = 1.f, sh0 = 0.f, sh1 = 0.f;
    if (!FIRST) { sc0 = scale[c0]; sc1 = scale[c0 + 1]; sh0 = shift[c0]; sh1 = shift[c0 + 1]; }
    const int beg = binBase[bin], end = binBase[bin + 1];
    for (int j = beg; j < end; j += 64) {
        const int n = min(64, end - j);
        int2 ed = (j + lane < end) ? edges[j + lane] : make_int2(0, 0);
        const int n16 = n & ~15;
        int t = 0;
        for (; t < n16; t += 16) {     // 16 edges per iter (8 per half), 8 loads in flight
            int sd_[8]; float wt_[8]; unsigned u_[8];
#pragma unroll
            for (int q = 0; q < 8; ++q) {
                const int ii = t + 2 * q + half;
                sd_[q] = __shfl(ed.x, ii);
                wt_[q] = __int_as_float(__shfl(ed.y, ii));
            }
#pragma unroll
            for (int q = 0; q < 8; ++q) u_[q] = hbf[(size_t)(sd_[q] >> 3) * 32 + p];
#pragma unroll
            for (int q = 0; q < 8; ++q) {
                float h0 = __uint_as_float(u_[q] << 16);
                float h1 = __uint_as_float(u_[q] & 0xFFFF0000u);
                if (!FIRST) { h0 = fmaf(h0, sc0, sh0); h1 = fmaf(h1, sc1, sh1); }
                float2* a2 = (float2*)&ac[(sd_[q] & 7) * 64 + c0];
                float2 v = *a2;
                v.x = fmaf(wt_[q], h0, v.x);
                v.y = fmaf(wt_[q], h1, v.y);
                *a2 = v;
            }
        }
        for (; t < n; t += 2) {
            const int ii = min(t + half, n - 1);
            const int sd = __shfl(ed.x, ii);
            float wt = __int_as_float(__shfl(ed.y, ii));
            if (t + half >= n) wt = 0.f;
            const unsigned u = hbf[(size_t)(sd >> 3) * 32 + p];
            float h0 = __uint_as_float(u << 16);
            float h1 = __uint_as_float(u & 0xFFFF0000u);
            if (!FIRST) { h0 = fmaf(h0, sc0, sh0); h1 = fmaf(h1, sc1, sh1); }
            float2* a2 = (float2*)&ac[(sd & 7) * 64 + c0];
            float2 v = *a2;
            v.x = fmaf(wt, h0, v.x);
            v.y = fmaf(wt, h1, v.y);
            *a2 = v;
        }
    }
    const int nodeBase = bin * BINSZ;
#pragma unroll
    for (int r = 0; r < BINSZ; ++r)
        agg[(size_t)(nodeBase + r) * 64 + lane] =
            accAll[w][0][r * 64 + lane] + accAll[w][1][r * 64 + lane];
}

// ---- y = PReLU(agg @ W^T + bias) -> packed bf16. LDS-tiled SGEMM:
// block = 128 rows x 64 cols, thread = 4 rows (stride 32) x 8 cols. ----
__global__ __launch_bounds__(256) void gemm_kernel(const float* __restrict__ agg,
                                                   const float* __restrict__ W,
                                                   const float* __restrict__ bias,
                                                   const float* __restrict__ pa_ptr,
                                                   unsigned* __restrict__ ybf) {
    __shared__ float As[128 * 68];
    __shared__ float Wt[64 * 68];
    const int tid = threadIdx.x;
    const int base = blockIdx.x * 128;
    for (int i = tid; i < 2048; i += 256) {
        const int r = i >> 4;
        const int q = (i & 15) * 4;
        const int row = base + r;
        float4 v = make_float4(0.f, 0.f, 0.f, 0.f);
        if (row < NNODES) v = *(const float4*)(agg + (size_t)row * 64 + q);
        *(float4*)&As[r * 68 + q] = v;
    }
    for (int i = tid; i < 4096; i += 256)
        Wt[(i & 63) * 68 + (i >> 6)] = W[i];
    __syncthreads();

    const int tc = tid & 7;
    const int tr = tid >> 3;
    float acc[4][8];
#pragma unroll
    for (int j = 0; j < 4; ++j)
#pragma unroll
        for (int c = 0; c < 8; ++c) acc[j][c] = 0.f;

    for (int kc = 0; kc < 16; ++kc) {
        const int k0 = kc * 4;
        float Af[4][4];
#pragma unroll
        for (int j = 0; j < 4; ++j) {
            const float4 t = *(const float4*)&As[(tr + 32 * j) * 68 + k0];
            Af[j][0] = t.x; Af[j][1] = t.y; Af[j][2] = t.z; Af[j][3] = t.w;
        }
#pragma unroll
        for (int kk = 0; kk < 4; ++kk) {
            const float4 w0 = *(const float4*)&Wt[(k0 + kk) * 68 + tc * 8];
            const float4 w1 = *(const float4*)&Wt[(k0 + kk) * 68 + tc * 8 + 4];
#pragma unroll
            for (int j = 0; j < 4; ++j) {
                const float a = Af[j][kk];
                acc[j][0] = fmaf(a, w0.x, acc[j][0]);
                acc[j][1] = fmaf(a, w0.y, acc[j][1]);
                acc[j][2] = fmaf(a, w0.z, acc[j][2]);
                acc[j][3] = fmaf(a, w0.w, acc[j][3]);
                acc[j][4] = fmaf(a, w1.x, acc[j][4]);
                acc[j][5] = fmaf(a, w1.y, acc[j][5]);
                acc[j][6] = fmaf(a, w1.z, acc[j][6]);
                acc[j][7] = fmaf(a, w1.w, acc[j][7]);
            }
        }
    }

    const float pa = *pa_ptr;
    const float4 b0 = *(const float4*)(bias + tc * 8);
    const float4 b1 = *(const float4*)(bias + tc * 8 + 4);
#pragma unroll
    for (int j = 0; j < 4; ++j) {
        const int row = base + tr + 32 * j;
        if (row >= NNODES) continue;
        float o[8];
        o[0] = acc[j][0] + b0.x; o[1] = acc[j][1] + b0.y;
        o[2] = acc[j][2] + b0.z; o[3] = acc[j][3] + b0.w;
        o[4] = acc[j][4] + b1.x; o[5] = acc[j][5] + b1.y;
        o[6] = acc[j][6] + b1.z; o[7] = acc[j][7] + b1.w;
#pragma unroll
        for (int c = 0; c < 8; ++c) o[c] = (o[c] >= 0.f) ? o[c] : pa * o[c];
        uint4 pk;
        pk.x = pack_bf16(o[0], o[1]);
        pk.y = pack_bf16(o[2], o[3]);
        pk.z = pack_bf16(o[4], o[5]);
        pk.w = pack_bf16(o[6], o[7]);
        *(uint4*)(ybf + (size_t)row * 32 + tc * 4) = pk;
    }
}

// ---- block = (graph, slice): graph-sum + channel sumsq from packed y.
// uint4 loads: wave reads 8 consecutive rows x 128 B = 1 KB coalesced per issue.
// graph-sum partials double as BN channel-sum partials (same rows). ----
__global__ __launch_bounds__(256) void stats_kernel(const unsigned* __restrict__ ybf,
                                                    const int* __restrict__ endv,
                                                    float* __restrict__ gsum4,
                                                    float* __restrict__ pQ4) {
    __shared__ float red[2][32][66];
    const int g = blockIdx.x >> 2, s = blockIdx.x & 3;
    const int t = threadIdx.x, rg = t >> 3, cg = t & 7;   // 32 row-groups x 8 col-groups
    const int g0 = (g == 0) ? 0 : endv[g - 1];
    const int g1 = endv[g];
    const int len = g1 - g0;
    const int q0 = g0 + (len * s) / SLICES;
    const int q1 = g0 + (len * (s + 1)) / SLICES;
    float sm[8], sq[8];
#pragma unroll
    for (int k = 0; k < 8; ++k) { sm[k] = 0.f; sq[k] = 0.f; }
    for (int r = q0 + rg; r < q1; r += 32) {
        const uint4 u4 = *(const uint4*)&ybf[(size_t)r * 32 + cg * 4];
        const unsigned uu[4] = {u4.x, u4.y, u4.z, u4.w};
#pragma unroll
        for (int k = 0; k < 4; ++k) {
            const float f0 = __uint_as_float(uu[k] << 16);
            const float f1 = __uint_as_float(uu[k] & 0xFFFF0000u);
            sm[2 * k] += f0; sm[2 * k + 1] += f1;
            sq[2 * k] = fmaf(f0, f0, sq[2 * k]);
            sq[2 * k + 1] = fmaf(f1, f1, sq[2 * k + 1]);
        }
    }
#pragma unroll
    for (int k = 0; k < 8; ++k) {
        red[0][rg][cg * 8 + k] = sm[k];
        red[1][rg][cg * 8 + k] = sq[k];
    }
    __syncthreads();
    if (t < 128) {
        const int which = t >> 6, c = t & 63;
        float a = 0.f;
#pragma unroll
        for (int k = 0; k < 32; ++k) a += red[which][k][c];
        if (which == 0) gsum4[blockIdx.x * 64 + c] = a;
        else            pQ4[blockIdx.x * 64 + c] = a;
    }
}

// ---- single block: BN closure + pooled outputs straight into d_out ----
__global__ __launch_bounds__(512) void finalize_kernel(const float* __restrict__ gsum4,
                                                       const float* __restrict__ pQ4,
                                                       const int* __restrict__ endv,
                                                       const float* __restrict__ bn_w,
                                                       const float* __restrict__ bn_b,
                                                       float* __restrict__ scale,
                                                       float* __restrict__ shift,
                                                       float* __restrict__ out, int layer) {
    __shared__ float rS[8][64], rQ[8][64];
    __shared__ float ssc[64], ssh[64];
    const int tid = threadIdx.x;
    const int c = tid & 63, pp = tid >> 6;    // pp in 0..7
    float S = 0.f, Q = 0.f;
    for (int sl = pp; sl < NGRAPHS * SLICES; sl += 8) {
        S += gsum4[sl * 64 + c];
        Q += pQ4[sl * 64 + c];
    }
    rS[pp][c] = S; rQ[pp][c] = Q;
    __syncthreads();
    if (tid < 64) {
        float SS = 0.f, QQ = 0.f;
#pragma unroll
        for (int k = 0; k < 8; ++k) { SS += rS[k][c]; QQ += rQ[k][c]; }
        const float mean = SS * (1.f / NNODES);
        const float var = fmaxf(QQ * (1.f / NNODES) - mean * mean, 0.f);
        const float inv = rsqrtf(var + BN_EPS);
        const float scv = inv * bn_w[c];
        const float shv = bn_b[c] - mean * scv;
        ssc[c] = scv; ssh[c] = shv;
        scale[c] = scv; shift[c] = shv;
    }
    __syncthreads();
    for (int idx = tid; idx < NGRAPHS * 64; idx += 512) {
        const int g = idx >> 6, ch = idx & 63;
        float gs = 0.f;
#pragma unroll
        for (int sl = 0; sl < SLICES; ++sl) gs += gsum4[(g * SLICES + sl) * 64 + ch];
        const int cnt = endv[g] - ((g == 0) ? 0 : endv[g - 1]);
        const float pooled = gs * ssc[ch] + (float)cnt * ssh[ch];
        out[g * (NLAYERS * 64) + layer * 64 + ch] = pooled;
        if (layer == NLAYERS - 1) out[NGRAPHS * NLAYERS * 64 + idx] = pooled;
    }
}

extern "C" void kernel_launch(void* const* d_in, const int* in_sizes, int n_in,
                              void* d_out, int out_size, void* d_ws, size_t ws_size,
                              hipStream_t stream) {
    const float* x     = (const float*)d_in[0];
    const int*   ei    = (const int*)d_in[1];
    const float* ea    = (const float*)d_in[2];
    const int*   batch = (const int*)d_in[3];
    const float* W     = (const float*)d_in[4];
    const float* b     = (const float*)d_in[5];
    const float* pa    = (const float*)d_in[6];
    const float* bn_w  = (const float*)d_in[7];
    const float* bn_b  = (const float*)d_in[8];
    float* out = (float*)d_out;
    float* ws  = (float*)d_ws;
    int*   wsi = (int*)d_ws;

    int2*           edges   = (int2*)(wsi + OFF_EDGES);
    int*            binBase = wsi + OFF_BINBASE;
    float*          agg     = ws + OFF_AGG;
    unsigned*       ybf     = (unsigned*)(wsi + OFF_YBF);
    unsigned*       xbf     = (unsigned*)(wsi + OFF_XBF);
    unsigned short* counts  = (unsigned short*)(wsi + OFF_CNT);
    unsigned short* offs    = (unsigned short*)(wsi + OFF_OFS);
    int*            btot    = wsi + OFF_BTOT;
    float*          gsum4   = ws + OFF_GSUM4;
    float*          pQ4     = ws + OFF_PQ4;
    float*          scaleA  = ws + OFF_SCALE;
    float*          shiftA  = ws + OFF_SHIFT;
    int*            endv    = wsi + OFF_END;

    count_kernel<<<GBLK, 1024, 0, stream>>>(ei, x, batch, counts, xbf, endv);
    s1_kernel<<<(NBINS + 255) / 256, 256, 0, stream>>>(counts, offs, btot);
    s2_kernel<<<1, 1024, 0, stream>>>(btot, binBase);
    scatter_kernel<<<GBLK, 1024, 0, stream>>>(ei, ea, binBase, offs, edges);

    for (int l = 0; l < NLAYERS; ++l) {
        if (l == 0)
            agg_kernel<true><<<NBINS / 4, 256, 0, stream>>>(xbf, nullptr, nullptr,
                                                            binBase, edges, agg);
        else
            agg_kernel<false><<<NBINS / 4, 256, 0, stream>>>(ybf, scaleA + (l - 1) * 64,
                                                             shiftA + (l - 1) * 64,
                                                             binBase, edges, agg);
        gemm_kernel<<<(NNODES + 127) / 128, 256, 0, stream>>>(agg, W + l * 4096, b + l * 64,
                                                              pa, ybf);
        stats_kernel<<<NGRAPHS * SLICES, 256, 0, stream>>>(ybf, endv, gsum4, pQ4);
        finalize_kernel<<<1, 512, 0, stream>>>(gsum4, pQ4, endv, bn_w + l * 64,
                                               bn_b + l * 64, scaleA + l * 64,
                                               shiftA + l * 64, out, l);
    }
}